// Round 2
// baseline (358.216 us; speedup 1.0000x reference)
//
#include <hip/hip_runtime.h>

// HiPPO-LegT projection: c_{t+1} = A c_t + B f_t, emit all 512 states.
// Round 2 structure:
//   power_kernel: A^d for d=1..64 (binary exp, f32 LDS), -> Tg carry slabs,
//                 K_d = A^d B, A^64 (f32) for the scan.
//   pack_kernel:  Tg tap slabs  Tg[(tau*64+n)][64+j] = (j<=tau)?K_{tau-j}[n]:0
//   scan_kernel:  f32 prescan of the 8 chunk-boundary carries
//                 c_{k+1} = A^64 c_k + sum_j A^{63-j} B f[64k+j]  -> bound[8]
//   chunk_gemm:   ONE launch, grid (32,16,8): per chunk GEMM
//                 M=2048(seq) x N=4096(tau,n) x K=128([carry|f]) in fp16 MFMA,
//                 W-fragment as MFMA A-operand so D rows = n -> dwordx4 stores.

typedef _Float16 half8  __attribute__((ext_vector_type(8)));
typedef _Float16 half4t __attribute__((ext_vector_type(4)));
typedef float    f32x4  __attribute__((ext_vector_type(4)));

#define SEQN 2048
#define LT   512

// ---------------------------------------------------------------------------
// 64x64 f32 matmul in LDS: C = X*Y given XT (X transposed) and Y.
// 512 threads, 4x2 block each. Optional transposed/normal result writes.
__device__ __forceinline__ void mul64(const float* XT, const float* Y,
                                      float* outT, float* outN, int t) {
  const int r = (t >> 5) * 4;
  const int c = (t & 31) * 2;
  float a00 = 0.f, a01 = 0.f, a10 = 0.f, a11 = 0.f;
  float a20 = 0.f, a21 = 0.f, a30 = 0.f, a31 = 0.f;
#pragma unroll 4
  for (int l = 0; l < 64; ++l) {
    const float4 x = *(const float4*)(XT + l * 64 + r);
    const float2 y = *(const float2*)(Y + l * 64 + c);
    a00 += x.x * y.x; a01 += x.x * y.y;
    a10 += x.y * y.x; a11 += x.y * y.y;
    a20 += x.z * y.x; a21 += x.z * y.y;
    a30 += x.w * y.x; a31 += x.w * y.y;
  }
  __syncthreads();
  if (outT) {
    outT[(c + 0) * 64 + r + 0] = a00; outT[(c + 1) * 64 + r + 0] = a01;
    outT[(c + 0) * 64 + r + 1] = a10; outT[(c + 1) * 64 + r + 1] = a11;
    outT[(c + 0) * 64 + r + 2] = a20; outT[(c + 1) * 64 + r + 2] = a21;
    outT[(c + 0) * 64 + r + 3] = a30; outT[(c + 1) * 64 + r + 3] = a31;
  }
  if (outN) {
    outN[(r + 0) * 64 + c + 0] = a00; outN[(r + 0) * 64 + c + 1] = a01;
    outN[(r + 1) * 64 + c + 0] = a10; outN[(r + 1) * 64 + c + 1] = a11;
    outN[(r + 2) * 64 + c + 0] = a20; outN[(r + 2) * 64 + c + 1] = a21;
    outN[(r + 3) * 64 + c + 0] = a30; outN[(r + 3) * 64 + c + 1] = a31;
  }
  __syncthreads();
}

// Block d (= blockIdx.x+1, 1..64): A^d by binary exponentiation (all f32).
__global__ __launch_bounds__(512) void power_kernel(
    const float* __restrict__ A, const float* __restrict__ B,
    _Float16* __restrict__ Tg, float* __restrict__ Kg,
    float* __restrict__ A64g) {
  __shared__ float S[4096];    // square-chain power (normal layout)
  __shared__ float STr[4096];  // same, transposed
  __shared__ float RT[4096];   // accumulated result, transposed
  const int t = threadIdx.x;
  const int d = blockIdx.x + 1;

  for (int i = t; i < 4096; i += 512) {
    const float v = A[i];
    S[i] = v;
    STr[(i & 63) * 64 + (i >> 6)] = v;
  }
  __syncthreads();

  bool rvalid = false;
  int e = d;
  while (e) {
    if (e & 1) {
      if (!rvalid) {
        for (int i = t; i < 4096; i += 512) RT[i] = STr[i];  // R = S
        rvalid = true;
        __syncthreads();
      } else {
        mul64(RT, S, RT, nullptr, t);  // R = R*S (transposed store)
      }
    }
    e >>= 1;
    if (e) mul64(STr, S, STr, S, t);   // S = S*S
  }
  // RT[m*64+n] = (A^d)[n][m]. Carry slab: Tg[((d-1)*64+n)][m] = A^d[n][m].
  for (int i = t; i < 4096; i += 512) {
    const int n = i >> 6, m = i & 63;
    Tg[(size_t)((d - 1) * 64 + n) * 128 + m] = (_Float16)RT[m * 64 + n];
  }
  // K_d = A^d B (f32); K_0 = B from block 1.
  if (d < 64 && t < 64) {
    float s = 0.f;
    for (int m = 0; m < 64; ++m) s += RT[m * 64 + t] * B[m];
    Kg[d * 64 + t] = s;
  }
  if (d == 1 && t < 64) Kg[t] = B[t];
  // A^64 in f32 for the boundary scan: A64g[n*64+m] = A^64[n][m].
  if (d == 64) {
    for (int i = t; i < 4096; i += 512) {
      const int n = i >> 6, m = i & 63;
      A64g[i] = RT[m * 64 + n];
    }
  }
}

// Block tau: tap slabs Tg[(tau*64+n)][64+j] = (j<=tau)?K_{tau-j}[n]:0.
__global__ __launch_bounds__(256) void pack_kernel(
    const float* __restrict__ Kg, _Float16* __restrict__ Tg) {
  const int tau = blockIdx.x;
  const int t = threadIdx.x;
  const int n = t >> 2;
  const int j0 = (t & 3) * 16;
#pragma unroll
  for (int jj = 0; jj < 16; ++jj) {
    const int j = j0 + jj;
    const _Float16 v =
        (j <= tau) ? (_Float16)Kg[(tau - j) * 64 + n] : (_Float16)0.f;
    Tg[(size_t)(tau * 64 + n) * 128 + 64 + j] = v;
  }
}

// f32 prescan of chunk-boundary states. Block = 4 sequences, thread = (s,n).
// bound[k][seq][n] = c at the START of chunk k (bound[0] = 0).
__global__ __launch_bounds__(256) void scan_kernel(
    const float* __restrict__ f, const float* __restrict__ A64g,
    const float* __restrict__ Kg, float* __restrict__ bound) {
  __shared__ float A64s[64 * 65];  // stride 65: lanes n -> banks n+j (2-way)
  __shared__ float Kxs[64 * 65];   // Kx[n][j] = K_{63-j}[n]
  __shared__ float fs[4][64];
  __shared__ float cs[4][64];
  const int tid = threadIdx.x;
  const int n = tid & 63, s = tid >> 6;
  const int seq = blockIdx.x * 4 + s;

  for (int i = tid; i < 4096; i += 256) {
    const int r = i >> 6, c = i & 63;
    A64s[r * 65 + c] = A64g[i];
    Kxs[r * 65 + c] = Kg[(63 - c) * 64 + r];
  }
  cs[s][n] = 0.f;
  bound[(size_t)seq * 64 + n] = 0.f;  // carry for chunk 0
  __syncthreads();

  for (int k = 0; k < 8; ++k) {
    fs[s][n] = f[(size_t)seq * LT + k * 64 + n];
    __syncthreads();
    float u = 0.f, v = 0.f;
#pragma unroll 8
    for (int j = 0; j < 64; ++j) {
      u += Kxs[n * 65 + j] * fs[s][j];
      v += A64s[n * 65 + j] * cs[s][j];
    }
    __syncthreads();
    const float cn = u + v;
    cs[s][n] = cn;
    if (k < 7) bound[((size_t)(k + 1) * SEQN + seq) * 64 + n] = cn;
    __syncthreads();
  }
}

// Fused chunk GEMM: grid (bn=32, bm=16, chunk=8). Out-tile 128(seq)x128(col),
// K=128. W-fragment is the MFMA A-operand: D row = n, D col = seq ->
// f32x4 stores, 16 per lane, each instr = 16 rows x 64B contiguous.
__global__ __launch_bounds__(256) void chunk_gemm(
    const float* __restrict__ f, const _Float16* __restrict__ Tg,
    const float* __restrict__ bound, float* __restrict__ out) {
  __shared__ _Float16 Xs[128 * 136];  // [seq-local][k], pad 8 -> 2-way max
  __shared__ _Float16 Ws[128 * 72];   // [col-local][kw], one 64-wide K half

  const int tid = threadIdx.x;
  const int bn = blockIdx.x, bm = blockIdx.y, chunk = blockIdx.z;
  const int lane = tid & 63, wid = tid >> 6;
  const int wm = wid >> 1, wn = wid & 1;
  const int l15 = lane & 15, quad = lane >> 4;
  const float* carry = bound + (size_t)chunk * SEQN * 64;

  // ---- stage X = [carry | f] (f32 -> f16) ----
  {
    const int r = tid >> 1, h = tid & 1;
    const int seq = bm * 128 + r;
    const float4* s = h ? (const float4*)(f + (size_t)seq * LT + chunk * 64)
                        : (const float4*)(carry + (size_t)seq * 64);
    _Float16* dst = &Xs[r * 136 + h * 64];
#pragma unroll
    for (int i = 0; i < 16; ++i) {
      const float4 v = s[i];
      half4t hv = {(_Float16)v.x, (_Float16)v.y, (_Float16)v.z, (_Float16)v.w};
      *(half4t*)(dst + i * 4) = hv;
    }
  }

  f32x4 acc[4][4];
  const f32x4 z = {0.f, 0.f, 0.f, 0.f};
#pragma unroll
  for (int i = 0; i < 4; ++i)
#pragma unroll
    for (int j = 0; j < 4; ++j) acc[i][j] = z;

  for (int kh = 0; kh < 2; ++kh) {
    if (kh) __syncthreads();  // protect Ws before overwrite
    // ---- stage W half (table rows are contiguous in K) ----
    {
      const int col = tid >> 1, h = tid & 1;
      const uint4* s = (const uint4*)(Tg + (size_t)(bn * 128 + col) * 128 +
                                      kh * 64 + h * 32);
#pragma unroll
      for (int i = 0; i < 4; ++i)
        *(uint4*)&Ws[col * 72 + h * 32 + i * 8] = s[i];
    }
    __syncthreads();

#pragma unroll
    for (int kk = 0; kk < 2; ++kk) {
      half8 wv[4], xv[4];
#pragma unroll
      for (int fm = 0; fm < 4; ++fm)
        wv[fm] = *(const half8*)&Ws[(wn * 64 + fm * 16 + l15) * 72 + kk * 32 +
                                    quad * 8];
#pragma unroll
      for (int fn = 0; fn < 4; ++fn)
        xv[fn] = *(const half8*)&Xs[(wm * 64 + fn * 16 + l15) * 136 + kh * 64 +
                                    kk * 32 + quad * 8];
#pragma unroll
      for (int fm = 0; fm < 4; ++fm)
#pragma unroll
        for (int fn = 0; fn < 4; ++fn)
          acc[fm][fn] = __builtin_amdgcn_mfma_f32_16x16x32_f16(
              wv[fm], xv[fn], acc[fm][fn], 0, 0, 0);
    }
  }

  // ---- epilogue: D row = n (= fm*16 + quad*4 + reg), D col = seq ----
  const int taug = chunk * 64 + bn * 2 + wn;
#pragma unroll
  for (int fm = 0; fm < 4; ++fm) {
#pragma unroll
    for (int fn = 0; fn < 4; ++fn) {
      const int seq = bm * 128 + wm * 64 + fn * 16 + l15;
      const int nb = fm * 16 + quad * 4;
      *(f32x4*)(out + ((size_t)taug * SEQN + seq) * 64 + nb) = acc[fm][fn];
    }
  }
}

extern "C" void kernel_launch(void* const* d_in, const int* in_sizes, int n_in,
                              void* d_out, int out_size, void* d_ws,
                              size_t ws_size, hipStream_t stream) {
  const float* f = (const float*)d_in[0];  // (16,128,512) -> (2048, 512)
  const float* A = (const float*)d_in[1];  // (64,64)
  const float* B = (const float*)d_in[2];  // (64,)
  float* out = (float*)d_out;              // (512, 2048, 64)

  char* ws = (char*)d_ws;
  _Float16* Tg = (_Float16*)ws;              // 4096 x 128 f16   = 1 MB
  float* Kg = (float*)(ws + (1 << 20));      // 64 x 64 f32      = 16 KB
  float* A64g = (float*)(ws + (1 << 20) + (16 << 10));  // 16 KB
  float* bound = (float*)(ws + (1 << 20) + (32 << 10)); // 8x2048x64 f32 = 4 MB

  power_kernel<<<64, 512, 0, stream>>>(A, B, Tg, Kg, A64g);
  pack_kernel<<<64, 256, 0, stream>>>(Kg, Tg);
  scan_kernel<<<512, 256, 0, stream>>>(f, A64g, Kg, bound);
  chunk_gemm<<<dim3(32, 16, 8), 256, 0, stream>>>(f, Tg, bound, out);
}